// Round 1
// baseline (3082.139 us; speedup 1.0000x reference)
//
#include <hip/hip_runtime.h>

#define N_NODES 100000
#define N_EDGES 1600000
#define DIM 64
#define NLAYER 4
#define NGRAPH 128
#define BN_EPS 1e-5f
#define NSHARD 16
#define AGG_CHUNK 16

typedef unsigned short ushort_t;
typedef unsigned int uint_t;
typedef __attribute__((ext_vector_type(8))) short short8;
typedef __attribute__((ext_vector_type(4))) float f32x4;

__device__ __forceinline__ ushort_t f2bf(float f) {
    uint_t u = __float_as_uint(f);
    uint_t r = (u + 0x7FFFu + ((u >> 16) & 1u)) >> 16;
    return (ushort_t)r;
}
__device__ __forceinline__ void bf8_to_f32(const uint4 v, float f[8]) {
    f[0] = __uint_as_float(v.x << 16);
    f[1] = __uint_as_float(v.x & 0xFFFF0000u);
    f[2] = __uint_as_float(v.y << 16);
    f[3] = __uint_as_float(v.y & 0xFFFF0000u);
    f[4] = __uint_as_float(v.z << 16);
    f[5] = __uint_as_float(v.z & 0xFFFF0000u);
    f[6] = __uint_as_float(v.w << 16);
    f[7] = __uint_as_float(v.w & 0xFFFF0000u);
}

// ---------------- CSR build (r7; k_fill now packs owner bits) ----------------

__global__ void k_hist(const int* __restrict__ ei, int* __restrict__ cntS,
                       int* __restrict__ rank) {
    int e = blockIdx.x * blockDim.x + threadIdx.x;
    if (e < N_EDGES) {
        int d = ei[N_EDGES + e];
        int s = blockIdx.x & (NSHARD - 1);
        rank[e] = atomicAdd(&cntS[s * N_NODES + d], 1);
    }
}

__global__ void k_sumsh(int* __restrict__ cntS, int* __restrict__ cnt) {
    int i = blockIdx.x * blockDim.x + threadIdx.x;
    if (i < N_NODES) {
        int run = 0;
#pragma unroll
        for (int s = 0; s < NSHARD; s++) {
            int c = cntS[s * N_NODES + i];
            cntS[s * N_NODES + i] = run;
            run += c;
        }
        cnt[i] = run;
    }
}

__global__ void k_scan1(const int* __restrict__ cnt, int* __restrict__ exc,
                        int* __restrict__ bsums) {
    __shared__ int s[256];
    int i = blockIdx.x * 256 + threadIdx.x;
    int v = (i < N_NODES) ? cnt[i] : 0;
    s[threadIdx.x] = v;
    __syncthreads();
    for (int off = 1; off < 256; off <<= 1) {
        int t = (threadIdx.x >= off) ? s[threadIdx.x - off] : 0;
        __syncthreads();
        s[threadIdx.x] += t;
        __syncthreads();
    }
    if (i < N_NODES) exc[i] = s[threadIdx.x] - v;
    if (threadIdx.x == 255) bsums[blockIdx.x] = s[255];
}

__global__ void k_scan2(const int* __restrict__ bsums, int* __restrict__ boffs, int nb) {
    __shared__ int s[512];
    int v = ((int)threadIdx.x < nb) ? bsums[threadIdx.x] : 0;
    s[threadIdx.x] = v;
    __syncthreads();
    for (int off = 1; off < 512; off <<= 1) {
        int t = (threadIdx.x >= off) ? s[threadIdx.x - off] : 0;
        __syncthreads();
        s[threadIdx.x] += t;
        __syncthreads();
    }
    if ((int)threadIdx.x < nb) boffs[threadIdx.x] = s[threadIdx.x] - v;
}

__global__ void k_scan3(int* __restrict__ exc, const int* __restrict__ boffs) {
    int i = blockIdx.x * 256 + threadIdx.x;
    if (i < N_NODES) exc[i] += boffs[blockIdx.x];
}

// csr entry = src | (dst & 15) << 20 : src < 2^17 fits in 20 bits; the
// owner-row-within-16-node-chunk rides in bits 20..23 so passA needs no
// per-edge owner search.
__global__ void k_fill(const int* __restrict__ ei, const int* __restrict__ rowptr,
                       const int* __restrict__ cntS, const int* __restrict__ rank,
                       int* __restrict__ csr) {
    int e = blockIdx.x * blockDim.x + threadIdx.x;
    if (e < N_EDGES) {
        int d = ei[N_EDGES + e];
        int s = blockIdx.x & (NSHARD - 1);
        csr[rowptr[d] + cntS[s * N_NODES + d] + rank[e]] =
            ei[e] | ((d & (AGG_CHUNK - 1)) << 20);
    }
}

__global__ void k_prep(const int* __restrict__ cnt, const int* __restrict__ batch,
                       float* __restrict__ invdeg, float* __restrict__ invg) {
    int i = blockIdx.x * blockDim.x + threadIdx.x;
    if (i < N_NODES) invdeg[i] = 1.0f / (float)max(cnt[i], 1);
    if (i < NGRAPH) {
        int key = i, lo = 0, hi = N_NODES;
        while (lo < hi) { int m = (lo + hi) >> 1; if (batch[m] < key) lo = m + 1; else hi = m; }
        int a = lo;
        key = i + 1; lo = 0; hi = N_NODES;
        while (lo < hi) { int m = (lo + hi) >> 1; if (batch[m] < key) lo = m + 1; else hi = m; }
        invg[i] = 1.0f / (float)max(lo - a, 1);
    }
}

__global__ void k_xcast(const float* __restrict__ x, ushort_t* __restrict__ xh) {
    int i = blockIdx.x * blockDim.x + threadIdx.x;
    if (i < N_NODES * 16) {
        const float4 v = ((const float4*)x)[i];
        ushort4 u;
        u.x = f2bf(v.x); u.y = f2bf(v.y); u.z = f2bf(v.z); u.w = f2bf(v.w);
        ((ushort4*)xh)[i] = u;
    }
}

// ---------------- Layer pass A: gather + MFMA GEMV(W1) + BN moments ----------
// r8 restructure for memory-level parallelism. The old pair loop drained
// vmcnt every iteration (idx -> gather -> shuffle-reduce): ~2 outstanding
// gathers/wave -> Little's-law ceiling ~2.4 TB/s (= measured). New scheme:
// per wave, process the 16-node chunk's edges FLAT, 64 per round:
//   - 1 coalesced load of 64 owner-packed csr entries (prefetched 1 round
//     ahead into 'nxt'),
//   - __shfl to hand edge (b*8+q) to lane group q, octet r = lane&7,
//   - 8 independent row gathers issued back-to-back (8-deep vmem queue),
//   - fp32 accumulate via LDS atomics into sacc[owner][col]; per-q column
//     rotation jj=(j+q)&7 turns the common all-same-owner batch into 64
//     distinct addresses (stride 65 dw => 2-way banks = free); dummy row 16
//     absorbs masked tail slots.
// Epilogue builds MFMA A-fragments in registers from sacc (+self +invdeg).

#define UNROLL_B 8   // 8 batches x 8 edges = 64 edges per round

__global__ __launch_bounds__(256, 4)
void k_passA(const ushort_t* __restrict__ h, const float* __restrict__ W1,
             const float* __restrict__ b1,
             const int* __restrict__ rowptr, const int* __restrict__ cnt,
             const int* __restrict__ csr, const float* __restrict__ invdeg,
             float* __restrict__ z, float* __restrict__ colsum,
             float* __restrict__ colsumsq) {
    __shared__ ushort_t wfrag[512 * 8];     // [(hh*4+c)*64+lane] -> 8 bf16
    __shared__ float sacc[4][17 * 65];      // per-wave fp32 acc, stride 65 dw
    __shared__ float red[128];              // block partial colsum / colsumsq

    const int w = threadIdx.x >> 6;
    const int lane = threadIdx.x & 63;
    const int q = lane >> 3;
    const int r = lane & 7;
    const int wid = __builtin_amdgcn_readfirstlane((blockIdx.x << 2) | w);
    const bool active = wid < (N_NODES / AGG_CHUNK);
    const int n0 = (active ? wid : 0) * AGG_CHUNK;

    // build W1 bf16 B-fragments: slot (hh,c,L): j -> W1[hh*32+(L>>4)*8+j][c*16+(L&15)]
    for (int s = threadIdx.x; s < 512; s += 256) {
        const int hh = s >> 8, c = (s >> 6) & 3, L = s & 63;
        const int kb = hh * 32 + ((L >> 4) * 8);
        const int out = c * 16 + (L & 15);
        uint_t* dst = (uint_t*)&wfrag[s * 8];
#pragma unroll
        for (int j2 = 0; j2 < 4; j2++) {
            const float lo = W1[(kb + 2 * j2) * 64 + out];
            const float hi = W1[(kb + 2 * j2 + 1) * 64 + out];
            dst[j2] = (uint_t)f2bf(lo) | ((uint_t)f2bf(hi) << 16);
        }
    }
    for (int t = lane; t < 17 * 65; t += 64) sacc[w][t] = 0.f;
    if (threadIdx.x < 128) red[threadIdx.x] = 0.f;
    __syncthreads();

    if (active) {
        const int base = rowptr[n0];
        const int endp = (wid == (N_NODES / AGG_CHUNK) - 1) ? N_EDGES
                                                            : rowptr[n0 + AGG_CHUNK];
        const int S = endp - base;
        if (S > 0) {
            const int nr = (S + 63) >> 6;
            uint_t cur = (uint_t)csr[base + min(lane, S - 1)];
            for (int ro = 0; ro < nr; ro++) {
                uint_t nxt = 0;
                if (ro + 1 < nr)
                    nxt = (uint_t)csr[base + min((ro + 1) * 64 + lane, S - 1)];
                const int elim = S - ro * 64;   // real edges this round
                uint4 g[UNROLL_B];
                int ow[UNROLL_B];
#pragma unroll
                for (int b = 0; b < UNROLL_B; b++) {
                    const uint_t entry = (uint_t)__shfl((int)cur, b * 8 + q, 64);
                    ow[b] = (b * 8 + q < elim) ? (int)(entry >> 20) : 16;
                    const size_t idx = (size_t)(entry & 0xFFFFFu);
                    g[b] = *(const uint4*)(h + (idx << 6) + (r << 3));
                }
#pragma unroll
                for (int b = 0; b < UNROLL_B; b++) {
                    float f[8];
                    bf8_to_f32(g[b], f);
                    float* row = &sacc[w][ow[b] * 65 + r * 8];
#pragma unroll
                    for (int j = 0; j < 8; j++) {
                        const int jj = (j + q) & 7;
                        atomicAdd(&row[jj], f[jj]);
                    }
                }
                cur = nxt;
            }
        }
    }
    __syncthreads();

    // epilogue: t[m][k] = sacc[m][k]*invdeg[m] + h_self[m][k], pack bf16,
    // A layout: m=lane&15, k=quad*8+j (two K-halves) [m120]
    const int m = lane & 15;
    const int quad = lane >> 4;
    const float id = invdeg[n0 + m];
    const ushort_t* hs = h + ((size_t)(n0 + m) << 6);
    const uint4 s0 = *(const uint4*)(hs + quad * 8);
    const uint4 s1 = *(const uint4*)(hs + 32 + quad * 8);
    float sf0[8], sf1[8];
    bf8_to_f32(s0, sf0);
    bf8_to_f32(s1, sf1);
    const float* arow = &sacc[w][m * 65];
    union { uint_t u[4]; short8 v; } pa0, pa1;
#pragma unroll
    for (int j2 = 0; j2 < 4; j2++) {
        const float lo0 = fmaf(arow[quad * 8 + 2 * j2],      id, sf0[2 * j2]);
        const float hi0 = fmaf(arow[quad * 8 + 2 * j2 + 1],  id, sf0[2 * j2 + 1]);
        pa0.u[j2] = (uint_t)f2bf(lo0) | ((uint_t)f2bf(hi0) << 16);
        const float lo1 = fmaf(arow[32 + quad * 8 + 2 * j2],     id, sf1[2 * j2]);
        const float hi1 = fmaf(arow[32 + quad * 8 + 2 * j2 + 1], id, sf1[2 * j2 + 1]);
        pa1.u[j2] = (uint_t)f2bf(lo1) | ((uint_t)f2bf(hi1) << 16);
    }
    const short8 a0 = pa0.v;
    const short8 a1 = pa1.v;

    float lsum[4], lsq[4];
#pragma unroll
    for (int c = 0; c < 4; c++) {
        const short8 b0 = *(const short8*)&wfrag[(size_t)(c * 64 + lane) * 8];
        const short8 b1f = *(const short8*)&wfrag[(size_t)((4 + c) * 64 + lane) * 8];
        f32x4 D = {0.f, 0.f, 0.f, 0.f};
        D = __builtin_amdgcn_mfma_f32_16x16x32_bf16(a0, b0, D, 0, 0, 0);
        D = __builtin_amdgcn_mfma_f32_16x16x32_bf16(a1, b1f, D, 0, 0, 0);
        const float bv = b1[c * 16 + m];
        float s = 0.f, sq = 0.f;
#pragma unroll
        for (int reg = 0; reg < 4; reg++) {
            const float zv = D[reg] + bv;
            if (active) {
                const int node = n0 + quad * 4 + reg;
                z[(size_t)node * 64 + c * 16 + m] = zv;
            }
            s += zv;
            sq += zv * zv;
        }
        lsum[c] = s;
        lsq[c] = sq;
    }

    if (active) {
#pragma unroll
        for (int c = 0; c < 4; c++) {
            float s = lsum[c], sq = lsq[c];
            s += __shfl_xor(s, 16, 64);
            s += __shfl_xor(s, 32, 64);
            sq += __shfl_xor(sq, 16, 64);
            sq += __shfl_xor(sq, 32, 64);
            if (quad == 0) {
                atomicAdd(&red[c * 16 + m], s);
                atomicAdd(&red[64 + c * 16 + m], sq);
            }
        }
    }
    __syncthreads();
    if (threadIdx.x < 64) {
        atomicAdd(&colsum[threadIdx.x], red[threadIdx.x]);
        atomicAdd(&colsumsq[threadIdx.x], red[64 + threadIdx.x]);
    }
}

// ---------------- BN prep ----------------

__global__ void k_bnprep(float* __restrict__ colsum, float* __restrict__ colsumsq,
                         const float* __restrict__ gamma, const float* __restrict__ beta,
                         float* __restrict__ scale, float* __restrict__ shift) {
    int j = threadIdx.x;  // 64 threads
    float invn = 1.0f / (float)N_NODES;
    float mu = colsum[j] * invn;
    float var = colsumsq[j] * invn - mu * mu;
    float rsg = rsqrtf(var + BN_EPS);
    float sc = gamma[j] * rsg;
    scale[j] = sc;
    shift[j] = beta[j] - mu * sc;
    colsum[j] = 0.f;
    colsumsq[j] = 0.f;
}

// ---------------- Layer pass B: BN + ReLU + GEMV(W2) + pools (r7) ------------

#define CHUNK_M 28  // multiple of 4

__global__ __launch_bounds__(256, 4)
void k_passB(const float* __restrict__ z, const float* __restrict__ W2,
             const float* __restrict__ b2, const float* __restrict__ scale,
             const float* __restrict__ shift, const int* __restrict__ batch,
             ushort_t* __restrict__ hout, float* __restrict__ node_pool,
             float* __restrict__ gacc, int first) {
    const int lane = threadIdx.x & 63;
    int wid_raw = (blockIdx.x << 2) | (threadIdx.x >> 6);
    const int wid = __builtin_amdgcn_readfirstlane(wid_raw);
    const int n0 = wid * CHUNK_M;
    const int n1 = min(N_NODES, n0 + CHUNK_M);

    float w[64];
#pragma unroll
    for (int k = 0; k < 64; k++) w[k] = W2[k * 64 + lane];
#pragma unroll
    for (int k = 0; k < 64; k++) asm("" : "+v"(w[k]));
    const float bj = b2[lane], sc = scale[lane], sh = shift[lane];

    int curg = -1;
    float ga = 0.f;
    for (int n = n0; n + 4 <= n1; n += 4) {
        float ra = fmaxf(fmaf(z[(size_t)n * 64 + lane], sc, sh), 0.f);
        float rb = fmaxf(fmaf(z[(size_t)(n + 1) * 64 + lane], sc, sh), 0.f);
        float rc = fmaxf(fmaf(z[(size_t)(n + 2) * 64 + lane], sc, sh), 0.f);
        float rd = fmaxf(fmaf(z[(size_t)(n + 3) * 64 + lane], sc, sh), 0.f);
        float ha = bj, hb = bj, hc = bj, hd = bj;
#pragma unroll
        for (int k = 0; k < 64; k++) {
            float ka = __int_as_float(__builtin_amdgcn_readlane(__float_as_int(ra), k));
            float kb = __int_as_float(__builtin_amdgcn_readlane(__float_as_int(rb), k));
            float kc = __int_as_float(__builtin_amdgcn_readlane(__float_as_int(rc), k));
            float kd = __int_as_float(__builtin_amdgcn_readlane(__float_as_int(rd), k));
            ha = fmaf(ka, w[k], ha);
            hb = fmaf(kb, w[k], hb);
            hc = fmaf(kc, w[k], hc);
            hd = fmaf(kd, w[k], hd);
        }
        hout[(size_t)n * 64 + lane] = f2bf(ha);
        hout[(size_t)(n + 1) * 64 + lane] = f2bf(hb);
        hout[(size_t)(n + 2) * 64 + lane] = f2bf(hc);
        hout[(size_t)(n + 3) * 64 + lane] = f2bf(hd);
        if (first) {
            node_pool[(size_t)n * 64 + lane] = ha;
            node_pool[(size_t)(n + 1) * 64 + lane] = hb;
            node_pool[(size_t)(n + 2) * 64 + lane] = hc;
            node_pool[(size_t)(n + 3) * 64 + lane] = hd;
        } else {
            node_pool[(size_t)n * 64 + lane] += ha;
            node_pool[(size_t)(n + 1) * 64 + lane] += hb;
            node_pool[(size_t)(n + 2) * 64 + lane] += hc;
            node_pool[(size_t)(n + 3) * 64 + lane] += hd;
        }
        float hv[4] = {ha, hb, hc, hd};
#pragma unroll
        for (int j = 0; j < 4; j++) {
            int g = batch[n + j];
            if (g != curg) {
                if (curg >= 0) atomicAdd(&gacc[curg * 64 + lane], ga);
                ga = 0.f;
                curg = g;
            }
            ga += hv[j];
        }
    }
    if (curg >= 0) atomicAdd(&gacc[curg * 64 + lane], ga);
}

__global__ void k_gfinal(const float* __restrict__ gacc, const float* __restrict__ invg,
                         float* __restrict__ gout) {
    int i = blockIdx.x * blockDim.x + threadIdx.x;
    if (i < NGRAPH * 64) gout[i] = gacc[i] * invg[i >> 6];
}

// ---------------- launch ----------------

extern "C" void kernel_launch(void* const* d_in, const int* in_sizes, int n_in,
                              void* d_out, int out_size, void* d_ws, size_t ws_size,
                              hipStream_t stream) {
    (void)in_sizes; (void)n_in; (void)out_size; (void)ws_size;
    const float* x     = (const float*)d_in[0];
    const int*   ei    = (const int*)d_in[1];
    const int*   batch = (const int*)d_in[2];
    const float* W1    = (const float*)d_in[3];
    const float* b1    = (const float*)d_in[4];
    const float* gamma = (const float*)d_in[5];
    const float* beta  = (const float*)d_in[6];
    const float* W2    = (const float*)d_in[7];
    const float* b2    = (const float*)d_in[8];
    float* out = (float*)d_out;  // [N*64] node_pool, then [G*64] g_pool

    // element offsets (4B units)
    size_t o = 0;
    size_t o_cntS    = o; o += (size_t)NSHARD * N_NODES;
    size_t o_colsum  = o; o += 64;
    size_t o_colsq   = o; o += 64;
    size_t o_gacc    = o; o += (size_t)NGRAPH * 64;
    size_t zero_elems = o;
    size_t o_cnt     = o; o += N_NODES;
    size_t o_rowptr  = o; o += N_NODES;
    size_t o_bsums   = o; o += 512;
    size_t o_boffs   = o; o += 512;
    size_t o_invdeg  = o; o += N_NODES;
    size_t o_invg    = o; o += NGRAPH;
    size_t o_scale   = o; o += 64;
    size_t o_shift   = o; o += 64;
    size_t o_rank    = o; o += N_EDGES;
    size_t o_csr     = o; o += N_EDGES;
    size_t o_bufA    = o; o += (size_t)N_NODES * 64;   // z, fp32
    size_t o_bufB    = o; o += (size_t)N_NODES * 16;   // h,  bf16 (N*64 ushorts)
    size_t o_xh      = o; o += (size_t)N_NODES * 16;   // x,  bf16

    int*   wsi = (int*)d_ws;
    float* wsf = (float*)d_ws;
    int*      cntS   = wsi + o_cntS;
    float*    colsum = wsf + o_colsum;
    float*    colsq  = wsf + o_colsq;
    float*    gacc   = wsf + o_gacc;
    int*      cnt    = wsi + o_cnt;
    int*      rowptr = wsi + o_rowptr;
    int*      bsums  = wsi + o_bsums;
    int*      boffs  = wsi + o_boffs;
    float*    invdeg = wsf + o_invdeg;
    float*    invg   = wsf + o_invg;
    float*    scale  = wsf + o_scale;
    float*    shift  = wsf + o_shift;
    int*      rank   = wsi + o_rank;
    int*      csr    = wsi + o_csr;
    float*    bufA   = wsf + o_bufA;
    ushort_t* bufB   = (ushort_t*)(wsi + o_bufB);
    ushort_t* xh     = (ushort_t*)(wsi + o_xh);

    hipMemsetAsync(d_ws, 0, zero_elems * 4, stream);

    const int eb = (N_EDGES + 255) / 256;
    const int nb = (N_NODES + 255) / 256;  // 391 <= 512

    k_hist<<<eb, 256, 0, stream>>>(ei, cntS, rank);
    k_xcast<<<(N_NODES * 16 + 255) / 256, 256, 0, stream>>>(x, xh);
    k_sumsh<<<nb, 256, 0, stream>>>(cntS, cnt);
    k_scan1<<<nb, 256, 0, stream>>>(cnt, rowptr, bsums);
    k_scan2<<<1, 512, 0, stream>>>(bsums, boffs, nb);
    k_scan3<<<nb, 256, 0, stream>>>(rowptr, boffs);
    k_prep<<<nb, 256, 0, stream>>>(cnt, batch, invdeg, invg);
    k_fill<<<eb, 256, 0, stream>>>(ei, rowptr, cntS, rank, csr);

    const int gridA = (N_NODES / AGG_CHUNK + 3) / 4;                  // 1563
    const int gridM = (N_NODES + CHUNK_M * 4 - 1) / (CHUNK_M * 4);    // 893
    for (int l = 0; l < NLAYER; l++) {
        const ushort_t* h_in = (l == 0) ? xh : bufB;
        k_passA<<<gridA, 256, 0, stream>>>(h_in, W1 + l * 4096, b1 + l * 64,
                                           rowptr, cnt, csr, invdeg,
                                           bufA, colsum, colsq);
        k_bnprep<<<1, 64, 0, stream>>>(colsum, colsq, gamma + l * 64, beta + l * 64,
                                       scale, shift);
        k_passB<<<gridM, 256, 0, stream>>>(bufA, W2 + l * 4096, b2 + l * 64,
                                           scale, shift, batch,
                                           bufB, out, gacc, (l == 0) ? 1 : 0);
    }
    k_gfinal<<<32, 256, 0, stream>>>(gacc, invg, out + (size_t)N_NODES * 64);
}

// Round 2
// 671.715 us; speedup vs baseline: 4.5885x; 4.5885x over previous
//
#include <hip/hip_runtime.h>

#define N_NODES 100000
#define N_EDGES 1600000
#define DIM 64
#define NLAYER 4
#define NGRAPH 128
#define BN_EPS 1e-5f
#define NSHARD 16
#define AGG_CHUNK 16

typedef unsigned short ushort_t;
typedef unsigned int uint_t;
typedef __attribute__((ext_vector_type(8))) short short8;
typedef __attribute__((ext_vector_type(4))) float f32x4;

__device__ __forceinline__ ushort_t f2bf(float f) {
    uint_t u = __float_as_uint(f);
    uint_t r = (u + 0x7FFFu + ((u >> 16) & 1u)) >> 16;
    return (ushort_t)r;
}
__device__ __forceinline__ void bf8_to_f32(const uint4 v, float f[8]) {
    f[0] = __uint_as_float(v.x << 16);
    f[1] = __uint_as_float(v.x & 0xFFFF0000u);
    f[2] = __uint_as_float(v.y << 16);
    f[3] = __uint_as_float(v.y & 0xFFFF0000u);
    f[4] = __uint_as_float(v.z << 16);
    f[5] = __uint_as_float(v.z & 0xFFFF0000u);
    f[6] = __uint_as_float(v.w << 16);
    f[7] = __uint_as_float(v.w & 0xFFFF0000u);
}

// ---------------- CSR build (r7, k_fill restored to plain src) ----------------

__global__ void k_hist(const int* __restrict__ ei, int* __restrict__ cntS,
                       int* __restrict__ rank) {
    int e = blockIdx.x * blockDim.x + threadIdx.x;
    if (e < N_EDGES) {
        int d = ei[N_EDGES + e];
        int s = blockIdx.x & (NSHARD - 1);
        rank[e] = atomicAdd(&cntS[s * N_NODES + d], 1);
    }
}

__global__ void k_sumsh(int* __restrict__ cntS, int* __restrict__ cnt) {
    int i = blockIdx.x * blockDim.x + threadIdx.x;
    if (i < N_NODES) {
        int run = 0;
#pragma unroll
        for (int s = 0; s < NSHARD; s++) {
            int c = cntS[s * N_NODES + i];
            cntS[s * N_NODES + i] = run;
            run += c;
        }
        cnt[i] = run;
    }
}

__global__ void k_scan1(const int* __restrict__ cnt, int* __restrict__ exc,
                        int* __restrict__ bsums) {
    __shared__ int s[256];
    int i = blockIdx.x * 256 + threadIdx.x;
    int v = (i < N_NODES) ? cnt[i] : 0;
    s[threadIdx.x] = v;
    __syncthreads();
    for (int off = 1; off < 256; off <<= 1) {
        int t = (threadIdx.x >= off) ? s[threadIdx.x - off] : 0;
        __syncthreads();
        s[threadIdx.x] += t;
        __syncthreads();
    }
    if (i < N_NODES) exc[i] = s[threadIdx.x] - v;
    if (threadIdx.x == 255) bsums[blockIdx.x] = s[255];
}

__global__ void k_scan2(const int* __restrict__ bsums, int* __restrict__ boffs, int nb) {
    __shared__ int s[512];
    int v = ((int)threadIdx.x < nb) ? bsums[threadIdx.x] : 0;
    s[threadIdx.x] = v;
    __syncthreads();
    for (int off = 1; off < 512; off <<= 1) {
        int t = (threadIdx.x >= off) ? s[threadIdx.x - off] : 0;
        __syncthreads();
        s[threadIdx.x] += t;
        __syncthreads();
    }
    if ((int)threadIdx.x < nb) boffs[threadIdx.x] = s[threadIdx.x] - v;
}

__global__ void k_scan3(int* __restrict__ exc, const int* __restrict__ boffs) {
    int i = blockIdx.x * 256 + threadIdx.x;
    if (i < N_NODES) exc[i] += boffs[blockIdx.x];
}

__global__ void k_fill(const int* __restrict__ ei, const int* __restrict__ rowptr,
                       const int* __restrict__ cntS, const int* __restrict__ rank,
                       int* __restrict__ csr) {
    int e = blockIdx.x * blockDim.x + threadIdx.x;
    if (e < N_EDGES) {
        int d = ei[N_EDGES + e];
        int s = blockIdx.x & (NSHARD - 1);
        csr[rowptr[d] + cntS[s * N_NODES + d] + rank[e]] = ei[e];
    }
}

__global__ void k_prep(const int* __restrict__ cnt, const int* __restrict__ batch,
                       float* __restrict__ invdeg, float* __restrict__ invg) {
    int i = blockIdx.x * blockDim.x + threadIdx.x;
    if (i < N_NODES) invdeg[i] = 1.0f / (float)max(cnt[i], 1);
    if (i < NGRAPH) {
        int key = i, lo = 0, hi = N_NODES;
        while (lo < hi) { int m = (lo + hi) >> 1; if (batch[m] < key) lo = m + 1; else hi = m; }
        int a = lo;
        key = i + 1; lo = 0; hi = N_NODES;
        while (lo < hi) { int m = (lo + hi) >> 1; if (batch[m] < key) lo = m + 1; else hi = m; }
        invg[i] = 1.0f / (float)max(lo - a, 1);
    }
}

__global__ void k_xcast(const float* __restrict__ x, ushort_t* __restrict__ xh) {
    int i = blockIdx.x * blockDim.x + threadIdx.x;
    if (i < N_NODES * 16) {
        const float4 v = ((const float4*)x)[i];
        ushort4 u;
        u.x = f2bf(v.x); u.y = f2bf(v.y); u.z = f2bf(v.z); u.w = f2bf(v.w);
        ((ushort4*)xh)[i] = u;
    }
}

// ---------------- Layer pass A: gather + MFMA GEMV(W1) + BN moments ----------
// r9: node-centric register accumulation (r7 structure, NO LDS atomics — r8's
// fp32 LDS atomicAdd serialized the whole kernel), but the per-wave node loop
// now runs FOUR degree streams in lockstep (wave-uniform guards to dmax) with
// the 8-edge index loads software-pipelined one group ahead. Steady state:
// 4 outstanding row gathers + 4 outstanding idx loads per wave (r7 had ~2
// total with a serial idx->gather 2-miss chain). Octet layout unchanged:
// q=lane>>3 edge slot, r=lane&7 column octet.

__global__ __launch_bounds__(256, 4)
void k_passA(const ushort_t* __restrict__ h, const float* __restrict__ W1,
             const float* __restrict__ b1,
             const int* __restrict__ rowptr, const int* __restrict__ cnt,
             const int* __restrict__ csr, const float* __restrict__ invdeg,
             float* __restrict__ z, float* __restrict__ colsum,
             float* __restrict__ colsumsq) {
    __shared__ ushort_t wfrag[512 * 8];     // [(hh*4+c)*64+lane] -> 8 bf16
    __shared__ uint_t smt[4][16 * 36];      // per-wave t tile, row stride 36 dw
    __shared__ float red[128];              // block partial colsum / colsumsq

    const int w = threadIdx.x >> 6;
    const int lane = threadIdx.x & 63;
    const int q = lane >> 3;
    const int r = lane & 7;
    const int wid = __builtin_amdgcn_readfirstlane((blockIdx.x << 2) | w);
    const bool active = wid < (N_NODES / AGG_CHUNK);
    const int n0 = (active ? wid : 0) * AGG_CHUNK;

    // build W1 bf16 B-fragments: slot (hh,c,L): j -> W1[hh*32+(L>>4)*8+j][c*16+(L&15)]
    for (int s = threadIdx.x; s < 512; s += 256) {
        const int hh = s >> 8, c = (s >> 6) & 3, L = s & 63;
        const int kb = hh * 32 + ((L >> 4) * 8);
        const int out = c * 16 + (L & 15);
        uint_t* dst = (uint_t*)&wfrag[s * 8];
#pragma unroll
        for (int j2 = 0; j2 < 4; j2++) {
            const float lo = W1[(kb + 2 * j2) * 64 + out];
            const float hi = W1[(kb + 2 * j2 + 1) * 64 + out];
            dst[j2] = (uint_t)f2bf(lo) | ((uint_t)f2bf(hi) << 16);
        }
    }
    if (threadIdx.x < 128) red[threadIdx.x] = 0.f;
    __syncthreads();

    // gather 16 nodes in 4 quads, stage t rows as bf16 into smt
    if (active) {
        for (int pp = 0; pp < AGG_CHUNK; pp += 4) {
            const int n = n0 + pp;
            int dN[4];
            const int* cp[4];
            float idg[4];
#pragma unroll
            for (int s = 0; s < 4; s++) {
                cp[s] = csr + rowptr[n + s];
                dN[s] = cnt[n + s];
                idg[s] = invdeg[n + s];
            }

            float acc[4][8] = {{0,0,0,0,0,0,0,0},{0,0,0,0,0,0,0,0},
                               {0,0,0,0,0,0,0,0},{0,0,0,0,0,0,0,0}};
            int i0[4];
#pragma unroll
            for (int s = 0; s < 4; s++)
                i0[s] = (dN[s] > 0) ? cp[s][min(q, dN[s] - 1)] : 0;

            const int dmax = max(max(dN[0], dN[1]), max(dN[2], dN[3]));
            for (int e = 0; e < dmax; e += 8) {
                uint4 g[4];
#pragma unroll
                for (int s = 0; s < 4; s++)
                    if (e < dN[s])
                        g[s] = *(const uint4*)(h + ((size_t)(uint_t)i0[s] << 6) + (r << 3));
                int i1[4];
#pragma unroll
                for (int s = 0; s < 4; s++)
                    i1[s] = (e + 8 < dN[s]) ? cp[s][min(e + 8 + q, dN[s] - 1)] : 0;
#pragma unroll
                for (int s = 0; s < 4; s++) {
                    if (e < dN[s]) {
                        float f[8];
                        bf8_to_f32(g[s], f);
                        const float m = (e + q < dN[s]) ? 1.f : 0.f;
#pragma unroll
                        for (int j = 0; j < 8; j++) acc[s][j] = fmaf(f[j], m, acc[s][j]);
                        i0[s] = i1[s];
                    }
                }
            }

            // self rows (issue before the reduce so they overlap it)
            uint4 sv[4];
#pragma unroll
            for (int s = 0; s < 4; s++)
                sv[s] = *(const uint4*)(h + (size_t)(n + s) * 64 + r * 8);

            // reduce across q-groups: all lanes end up with column sums
#pragma unroll
            for (int s = 0; s < 4; s++)
#pragma unroll
                for (int j = 0; j < 8; j++) {
                    acc[s][j] += __shfl_xor(acc[s][j], 8, 64);
                    acc[s][j] += __shfl_xor(acc[s][j], 16, 64);
                    acc[s][j] += __shfl_xor(acc[s][j], 32, 64);
                }

            float sf[4][8];
#pragma unroll
            for (int s = 0; s < 4; s++) bf8_to_f32(sv[s], sf[s]);

            // per-lane select of the stream this q stages, then pack bf16
            float tsel[8];
#pragma unroll
            for (int j = 0; j < 8; j++) {
                const float t0 = fmaf(acc[0][j], idg[0], sf[0][j]);
                const float t1 = fmaf(acc[1][j], idg[1], sf[1][j]);
                const float t2 = fmaf(acc[2][j], idg[2], sf[2][j]);
                const float t3 = fmaf(acc[3][j], idg[3], sf[3][j]);
                tsel[j] = (q == 0) ? t0 : (q == 1) ? t1 : (q == 2) ? t2 : t3;
            }
            if (q < 4) {   // lane group q stages node pp+q
                uint_t* dst = &smt[w][(pp + q) * 36 + r * 4];
#pragma unroll
                for (int j2 = 0; j2 < 4; j2++)
                    dst[j2] = (uint_t)f2bf(tsel[2 * j2]) |
                              ((uint_t)f2bf(tsel[2 * j2 + 1]) << 16);
            }
        }
    }
    __syncthreads();

    // MFMA: A = t tile (m=lane&15, k=quad*8+j), two K-halves
    const int m = lane & 15;
    const int quad = lane >> 4;
    const short8 a0 = *(const short8*)&smt[w][m * 36 + quad * 4];
    const short8 a1 = *(const short8*)&smt[w][m * 36 + 16 + quad * 4];

    float lsum[4], lsq[4];
#pragma unroll
    for (int c = 0; c < 4; c++) {
        const short8 b0 = *(const short8*)&wfrag[(size_t)(c * 64 + lane) * 8];
        const short8 b1f = *(const short8*)&wfrag[(size_t)((4 + c) * 64 + lane) * 8];
        f32x4 D = {0.f, 0.f, 0.f, 0.f};
        D = __builtin_amdgcn_mfma_f32_16x16x32_bf16(a0, b0, D, 0, 0, 0);
        D = __builtin_amdgcn_mfma_f32_16x16x32_bf16(a1, b1f, D, 0, 0, 0);
        const float bv = b1[c * 16 + m];
        float s = 0.f, sq = 0.f;
#pragma unroll
        for (int reg = 0; reg < 4; reg++) {
            const float zv = D[reg] + bv;
            if (active) {
                const int node = n0 + quad * 4 + reg;
                z[(size_t)node * 64 + c * 16 + m] = zv;
            }
            s += zv;
            sq += zv * zv;
        }
        lsum[c] = s;
        lsq[c] = sq;
    }

    if (active) {
#pragma unroll
        for (int c = 0; c < 4; c++) {
            float s = lsum[c], sq = lsq[c];
            s += __shfl_xor(s, 16, 64);
            s += __shfl_xor(s, 32, 64);
            sq += __shfl_xor(sq, 16, 64);
            sq += __shfl_xor(sq, 32, 64);
            if (quad == 0) {
                atomicAdd(&red[c * 16 + m], s);
                atomicAdd(&red[64 + c * 16 + m], sq);
            }
        }
    }
    __syncthreads();
    if (threadIdx.x < 64) {
        atomicAdd(&colsum[threadIdx.x], red[threadIdx.x]);
        atomicAdd(&colsumsq[threadIdx.x], red[64 + threadIdx.x]);
    }
}

// ---------------- BN prep ----------------

__global__ void k_bnprep(float* __restrict__ colsum, float* __restrict__ colsumsq,
                         const float* __restrict__ gamma, const float* __restrict__ beta,
                         float* __restrict__ scale, float* __restrict__ shift) {
    int j = threadIdx.x;  // 64 threads
    float invn = 1.0f / (float)N_NODES;
    float mu = colsum[j] * invn;
    float var = colsumsq[j] * invn - mu * mu;
    float rsg = rsqrtf(var + BN_EPS);
    float sc = gamma[j] * rsg;
    scale[j] = sc;
    shift[j] = beta[j] - mu * sc;
    colsum[j] = 0.f;
    colsumsq[j] = 0.f;
}

// ---------------- Layer pass B: BN + ReLU + GEMV(W2) + pools (r7) ------------

#define CHUNK_M 28  // multiple of 4

__global__ __launch_bounds__(256, 4)
void k_passB(const float* __restrict__ z, const float* __restrict__ W2,
             const float* __restrict__ b2, const float* __restrict__ scale,
             const float* __restrict__ shift, const int* __restrict__ batch,
             ushort_t* __restrict__ hout, float* __restrict__ node_pool,
             float* __restrict__ gacc, int first) {
    const int lane = threadIdx.x & 63;
    int wid_raw = (blockIdx.x << 2) | (threadIdx.x >> 6);
    const int wid = __builtin_amdgcn_readfirstlane(wid_raw);
    const int n0 = wid * CHUNK_M;
    const int n1 = min(N_NODES, n0 + CHUNK_M);

    float w[64];
#pragma unroll
    for (int k = 0; k < 64; k++) w[k] = W2[k * 64 + lane];
#pragma unroll
    for (int k = 0; k < 64; k++) asm("" : "+v"(w[k]));
    const float bj = b2[lane], sc = scale[lane], sh = shift[lane];

    int curg = -1;
    float ga = 0.f;
    for (int n = n0; n + 4 <= n1; n += 4) {
        float ra = fmaxf(fmaf(z[(size_t)n * 64 + lane], sc, sh), 0.f);
        float rb = fmaxf(fmaf(z[(size_t)(n + 1) * 64 + lane], sc, sh), 0.f);
        float rc = fmaxf(fmaf(z[(size_t)(n + 2) * 64 + lane], sc, sh), 0.f);
        float rd = fmaxf(fmaf(z[(size_t)(n + 3) * 64 + lane], sc, sh), 0.f);
        float ha = bj, hb = bj, hc = bj, hd = bj;
#pragma unroll
        for (int k = 0; k < 64; k++) {
            float ka = __int_as_float(__builtin_amdgcn_readlane(__float_as_int(ra), k));
            float kb = __int_as_float(__builtin_amdgcn_readlane(__float_as_int(rb), k));
            float kc = __int_as_float(__builtin_amdgcn_readlane(__float_as_int(rc), k));
            float kd = __int_as_float(__builtin_amdgcn_readlane(__float_as_int(rd), k));
            ha = fmaf(ka, w[k], ha);
            hb = fmaf(kb, w[k], hb);
            hc = fmaf(kc, w[k], hc);
            hd = fmaf(kd, w[k], hd);
        }
        hout[(size_t)n * 64 + lane] = f2bf(ha);
        hout[(size_t)(n + 1) * 64 + lane] = f2bf(hb);
        hout[(size_t)(n + 2) * 64 + lane] = f2bf(hc);
        hout[(size_t)(n + 3) * 64 + lane] = f2bf(hd);
        if (first) {
            node_pool[(size_t)n * 64 + lane] = ha;
            node_pool[(size_t)(n + 1) * 64 + lane] = hb;
            node_pool[(size_t)(n + 2) * 64 + lane] = hc;
            node_pool[(size_t)(n + 3) * 64 + lane] = hd;
        } else {
            node_pool[(size_t)n * 64 + lane] += ha;
            node_pool[(size_t)(n + 1) * 64 + lane] += hb;
            node_pool[(size_t)(n + 2) * 64 + lane] += hc;
            node_pool[(size_t)(n + 3) * 64 + lane] += hd;
        }
        float hv[4] = {ha, hb, hc, hd};
#pragma unroll
        for (int j = 0; j < 4; j++) {
            int g = batch[n + j];
            if (g != curg) {
                if (curg >= 0) atomicAdd(&gacc[curg * 64 + lane], ga);
                ga = 0.f;
                curg = g;
            }
            ga += hv[j];
        }
    }
    if (curg >= 0) atomicAdd(&gacc[curg * 64 + lane], ga);
}

__global__ void k_gfinal(const float* __restrict__ gacc, const float* __restrict__ invg,
                         float* __restrict__ gout) {
    int i = blockIdx.x * blockDim.x + threadIdx.x;
    if (i < NGRAPH * 64) gout[i] = gacc[i] * invg[i >> 6];
}

// ---------------- launch ----------------

extern "C" void kernel_launch(void* const* d_in, const int* in_sizes, int n_in,
                              void* d_out, int out_size, void* d_ws, size_t ws_size,
                              hipStream_t stream) {
    (void)in_sizes; (void)n_in; (void)out_size; (void)ws_size;
    const float* x     = (const float*)d_in[0];
    const int*   ei    = (const int*)d_in[1];
    const int*   batch = (const int*)d_in[2];
    const float* W1    = (const float*)d_in[3];
    const float* b1    = (const float*)d_in[4];
    const float* gamma = (const float*)d_in[5];
    const float* beta  = (const float*)d_in[6];
    const float* W2    = (const float*)d_in[7];
    const float* b2    = (const float*)d_in[8];
    float* out = (float*)d_out;  // [N*64] node_pool, then [G*64] g_pool

    // element offsets (4B units)
    size_t o = 0;
    size_t o_cntS    = o; o += (size_t)NSHARD * N_NODES;
    size_t o_colsum  = o; o += 64;
    size_t o_colsq   = o; o += 64;
    size_t o_gacc    = o; o += (size_t)NGRAPH * 64;
    size_t zero_elems = o;
    size_t o_cnt     = o; o += N_NODES;
    size_t o_rowptr  = o; o += N_NODES;
    size_t o_bsums   = o; o += 512;
    size_t o_boffs   = o; o += 512;
    size_t o_invdeg  = o; o += N_NODES;
    size_t o_invg    = o; o += NGRAPH;
    size_t o_scale   = o; o += 64;
    size_t o_shift   = o; o += 64;
    size_t o_rank    = o; o += N_EDGES;
    size_t o_csr     = o; o += N_EDGES;
    size_t o_bufA    = o; o += (size_t)N_NODES * 64;   // z, fp32
    size_t o_bufB    = o; o += (size_t)N_NODES * 16;   // h,  bf16 (N*64 ushorts)
    size_t o_xh      = o; o += (size_t)N_NODES * 16;   // x,  bf16

    int*   wsi = (int*)d_ws;
    float* wsf = (float*)d_ws;
    int*      cntS   = wsi + o_cntS;
    float*    colsum = wsf + o_colsum;
    float*    colsq  = wsf + o_colsq;
    float*    gacc   = wsf + o_gacc;
    int*      cnt    = wsi + o_cnt;
    int*      rowptr = wsi + o_rowptr;
    int*      bsums  = wsi + o_bsums;
    int*      boffs  = wsi + o_boffs;
    float*    invdeg = wsf + o_invdeg;
    float*    invg   = wsf + o_invg;
    float*    scale  = wsf + o_scale;
    float*    shift  = wsf + o_shift;
    int*      rank   = wsi + o_rank;
    int*      csr    = wsi + o_csr;
    float*    bufA   = wsf + o_bufA;
    ushort_t* bufB   = (ushort_t*)(wsi + o_bufB);
    ushort_t* xh     = (ushort_t*)(wsi + o_xh);

    hipMemsetAsync(d_ws, 0, zero_elems * 4, stream);

    const int eb = (N_EDGES + 255) / 256;
    const int nb = (N_NODES + 255) / 256;  // 391 <= 512

    k_hist<<<eb, 256, 0, stream>>>(ei, cntS, rank);
    k_xcast<<<(N_NODES * 16 + 255) / 256, 256, 0, stream>>>(x, xh);
    k_sumsh<<<nb, 256, 0, stream>>>(cntS, cnt);
    k_scan1<<<nb, 256, 0, stream>>>(cnt, rowptr, bsums);
    k_scan2<<<1, 512, 0, stream>>>(bsums, boffs, nb);
    k_scan3<<<nb, 256, 0, stream>>>(rowptr, boffs);
    k_prep<<<nb, 256, 0, stream>>>(cnt, batch, invdeg, invg);
    k_fill<<<eb, 256, 0, stream>>>(ei, rowptr, cntS, rank, csr);

    const int gridA = (N_NODES / AGG_CHUNK + 3) / 4;                  // 1563
    const int gridM = (N_NODES + CHUNK_M * 4 - 1) / (CHUNK_M * 4);    // 893
    for (int l = 0; l < NLAYER; l++) {
        const ushort_t* h_in = (l == 0) ? xh : bufB;
        k_passA<<<gridA, 256, 0, stream>>>(h_in, W1 + l * 4096, b1 + l * 64,
                                           rowptr, cnt, csr, invdeg,
                                           bufA, colsum, colsq);
        k_bnprep<<<1, 64, 0, stream>>>(colsum, colsq, gamma + l * 64, beta + l * 64,
                                       scale, shift);
        k_passB<<<gridM, 256, 0, stream>>>(bufA, W2 + l * 4096, b2 + l * 64,
                                           scale, shift, batch,
                                           bufB, out, gacc, (l == 0) ? 1 : 0);
    }
    k_gfinal<<<32, 256, 0, stream>>>(gacc, invg, out + (size_t)N_NODES * 64);
}

// Round 3
// 571.749 us; speedup vs baseline: 5.3907x; 1.1748x over previous
//
#include <hip/hip_runtime.h>

#define N_NODES 100000
#define N_EDGES 1600000
#define DIM 64
#define NLAYER 4
#define NGRAPH 128
#define BN_EPS 1e-5f
#define NSHARD 16
#define AGG_CHUNK 16

typedef unsigned short ushort_t;
typedef unsigned int uint_t;
typedef __attribute__((ext_vector_type(8))) short short8;
typedef __attribute__((ext_vector_type(4))) float f32x4;

__device__ __forceinline__ ushort_t f2bf(float f) {
    uint_t u = __float_as_uint(f);
    uint_t r = (u + 0x7FFFu + ((u >> 16) & 1u)) >> 16;
    return (ushort_t)r;
}
__device__ __forceinline__ float bf2f(ushort_t u) {
    return __uint_as_float((uint_t)u << 16);
}
__device__ __forceinline__ void bf8_to_f32(const uint4 v, float f[8]) {
    f[0] = __uint_as_float(v.x << 16);
    f[1] = __uint_as_float(v.x & 0xFFFF0000u);
    f[2] = __uint_as_float(v.y << 16);
    f[3] = __uint_as_float(v.y & 0xFFFF0000u);
    f[4] = __uint_as_float(v.z << 16);
    f[5] = __uint_as_float(v.z & 0xFFFF0000u);
    f[6] = __uint_as_float(v.w << 16);
    f[7] = __uint_as_float(v.w & 0xFFFF0000u);
}

// ---------------- CSR build (r7, unchanged) ----------------

__global__ void k_hist(const int* __restrict__ ei, int* __restrict__ cntS,
                       int* __restrict__ rank) {
    int e = blockIdx.x * blockDim.x + threadIdx.x;
    if (e < N_EDGES) {
        int d = ei[N_EDGES + e];
        int s = blockIdx.x & (NSHARD - 1);
        rank[e] = atomicAdd(&cntS[s * N_NODES + d], 1);
    }
}

__global__ void k_sumsh(int* __restrict__ cntS, int* __restrict__ cnt) {
    int i = blockIdx.x * blockDim.x + threadIdx.x;
    if (i < N_NODES) {
        int run = 0;
#pragma unroll
        for (int s = 0; s < NSHARD; s++) {
            int c = cntS[s * N_NODES + i];
            cntS[s * N_NODES + i] = run;
            run += c;
        }
        cnt[i] = run;
    }
}

__global__ void k_scan1(const int* __restrict__ cnt, int* __restrict__ exc,
                        int* __restrict__ bsums) {
    __shared__ int s[256];
    int i = blockIdx.x * 256 + threadIdx.x;
    int v = (i < N_NODES) ? cnt[i] : 0;
    s[threadIdx.x] = v;
    __syncthreads();
    for (int off = 1; off < 256; off <<= 1) {
        int t = (threadIdx.x >= off) ? s[threadIdx.x - off] : 0;
        __syncthreads();
        s[threadIdx.x] += t;
        __syncthreads();
    }
    if (i < N_NODES) exc[i] = s[threadIdx.x] - v;
    if (threadIdx.x == 255) bsums[blockIdx.x] = s[255];
}

__global__ void k_scan2(const int* __restrict__ bsums, int* __restrict__ boffs, int nb) {
    __shared__ int s[512];
    int v = ((int)threadIdx.x < nb) ? bsums[threadIdx.x] : 0;
    s[threadIdx.x] = v;
    __syncthreads();
    for (int off = 1; off < 512; off <<= 1) {
        int t = (threadIdx.x >= off) ? s[threadIdx.x - off] : 0;
        __syncthreads();
        s[threadIdx.x] += t;
        __syncthreads();
    }
    if ((int)threadIdx.x < nb) boffs[threadIdx.x] = s[threadIdx.x] - v;
}

__global__ void k_scan3(int* __restrict__ exc, const int* __restrict__ boffs) {
    int i = blockIdx.x * 256 + threadIdx.x;
    if (i < N_NODES) exc[i] += boffs[blockIdx.x];
}

__global__ void k_fill(const int* __restrict__ ei, const int* __restrict__ rowptr,
                       const int* __restrict__ cntS, const int* __restrict__ rank,
                       int* __restrict__ csr) {
    int e = blockIdx.x * blockDim.x + threadIdx.x;
    if (e < N_EDGES) {
        int d = ei[N_EDGES + e];
        int s = blockIdx.x & (NSHARD - 1);
        csr[rowptr[d] + cntS[s * N_NODES + d] + rank[e]] = ei[e];
    }
}

__global__ void k_prep(const int* __restrict__ cnt, const int* __restrict__ batch,
                       float* __restrict__ invdeg, float* __restrict__ invg) {
    int i = blockIdx.x * blockDim.x + threadIdx.x;
    if (i < N_NODES) invdeg[i] = 1.0f / (float)max(cnt[i], 1);
    if (i < NGRAPH) {
        int key = i, lo = 0, hi = N_NODES;
        while (lo < hi) { int m = (lo + hi) >> 1; if (batch[m] < key) lo = m + 1; else hi = m; }
        int a = lo;
        key = i + 1; lo = 0; hi = N_NODES;
        while (lo < hi) { int m = (lo + hi) >> 1; if (batch[m] < key) lo = m + 1; else hi = m; }
        invg[i] = 1.0f / (float)max(lo - a, 1);
    }
}

__global__ void k_xcast(const float* __restrict__ x, ushort_t* __restrict__ xh) {
    int i = blockIdx.x * blockDim.x + threadIdx.x;
    if (i < N_NODES * 16) {
        const float4 v = ((const float4*)x)[i];
        ushort4 u;
        u.x = f2bf(v.x); u.y = f2bf(v.y); u.z = f2bf(v.z); u.w = f2bf(v.w);
        ((ushort4*)xh)[i] = u;
    }
}

// One masked group of 8 edges; bf16 rows, octet layout (q=lane>>3 edge slot,
// r=lane&7 column octet). 1 idx load + 1 dwordx4 gather per 8 edges.
__device__ __forceinline__ void grp8b(const ushort_t* __restrict__ h,
                                      const int* __restrict__ cp,
                                      int e, int deg, int q, int r,
                                      float acc[8]) {
    const int last = deg - 1;
    const int e0 = e + q;
    int i0 = cp[min(e0, last)];
    float m0 = (e0 < deg) ? 1.f : 0.f;
    const uint4 v = *(const uint4*)(h + (size_t)i0 * 64 + r * 8);
    float f[8];
    bf8_to_f32(v, f);
#pragma unroll
    for (int j = 0; j < 8; j++) acc[j] = fmaf(f[j], m0, acc[j]);
}

// ---------------- Layer pass A: gather + MFMA GEMV(W1) + BN moments ----------
// r10: exact r7 structure (77.7 us, known-good; r8/r9 MLP restructures proved
// the gather is SUPPLY-bound ~2.6 TB/s, not latency-bound). Changes: z stores
// are non-temporal (stop the 25.6 MB z stream evicting the 12.8 MB h table
// from L2), colsum/colsumsq are per-layer slices (bnprep fused into passB).

__global__ __launch_bounds__(256, 4)
void k_passA(const ushort_t* __restrict__ h, const float* __restrict__ W1,
             const float* __restrict__ b1,
             const int* __restrict__ rowptr, const int* __restrict__ cnt,
             const int* __restrict__ csr, const float* __restrict__ invdeg,
             float* __restrict__ z, float* __restrict__ colsum,
             float* __restrict__ colsumsq) {
    __shared__ ushort_t wfrag[512 * 8];     // [(hh*4+c)*64+lane] -> 8 bf16
    __shared__ uint_t smt[4][16 * 36];      // per-wave t tile, row stride 36 dw
    __shared__ float red[128];              // block partial colsum / colsumsq

    const int w = threadIdx.x >> 6;
    const int lane = threadIdx.x & 63;
    const int q = lane >> 3;
    const int r = lane & 7;
    const int wid = __builtin_amdgcn_readfirstlane((blockIdx.x << 2) | w);
    const bool active = wid < (N_NODES / AGG_CHUNK);
    const int n0 = (active ? wid : 0) * AGG_CHUNK;

    // build W1 bf16 B-fragments: slot (hh,c,L): j -> W1[hh*32+(L>>4)*8+j][c*16+(L&15)]
    for (int s = threadIdx.x; s < 512; s += 256) {
        const int hh = s >> 8, c = (s >> 6) & 3, L = s & 63;
        const int kb = hh * 32 + ((L >> 4) * 8);
        const int out = c * 16 + (L & 15);
        uint_t* dst = (uint_t*)&wfrag[s * 8];
#pragma unroll
        for (int j2 = 0; j2 < 4; j2++) {
            const float lo = W1[(kb + 2 * j2) * 64 + out];
            const float hi = W1[(kb + 2 * j2 + 1) * 64 + out];
            dst[j2] = (uint_t)f2bf(lo) | ((uint_t)f2bf(hi) << 16);
        }
    }
    if (threadIdx.x < 128) red[threadIdx.x] = 0.f;
    __syncthreads();

    // gather 16 nodes (8 pairs), stage t rows as bf16 into smt
    if (active) {
        for (int pp = 0; pp < AGG_CHUNK; pp += 2) {
            const int n = n0 + pp;
            const int sa = rowptr[n],     da = cnt[n];
            const int sb = rowptr[n + 1], db = cnt[n + 1];
            const float idga = invdeg[n], idgb = invdeg[n + 1];
            const int* __restrict__ ca = csr + sa;
            const int* __restrict__ cb = csr + sb;

            float aa[8] = {0,0,0,0,0,0,0,0};
            float ab[8] = {0,0,0,0,0,0,0,0};
            const int mm = min(da, db);
            int e = 0;
            for (; e < mm; e += 8) {
                grp8b(h, ca, e, da, q, r, aa);
                grp8b(h, cb, e, db, q, r, ab);
            }
            for (; e < da; e += 8) grp8b(h, ca, e, da, q, r, aa);
            for (; e < db; e += 8) grp8b(h, cb, e, db, q, r, ab);

#pragma unroll
            for (int j = 0; j < 8; j++) {
                aa[j] += __shfl_xor(aa[j], 8, 64);
                aa[j] += __shfl_xor(aa[j], 16, 64);
                aa[j] += __shfl_xor(aa[j], 32, 64);
                ab[j] += __shfl_xor(ab[j], 8, 64);
                ab[j] += __shfl_xor(ab[j], 16, 64);
                ab[j] += __shfl_xor(ab[j], 32, 64);
            }

            const uint4 sva = *(const uint4*)(h + (size_t)n * 64 + r * 8);
            const uint4 svb = *(const uint4*)(h + (size_t)(n + 1) * 64 + r * 8);
            float sa8[8], sb8[8];
            bf8_to_f32(sva, sa8);
            bf8_to_f32(svb, sb8);
            float ta[8], tb[8];
#pragma unroll
            for (int j = 0; j < 8; j++) {
                ta[j] = fmaf(aa[j], idga, sa8[j]);
                tb[j] = fmaf(ab[j], idgb, sb8[j]);
            }

            if (q < 2) {   // lanes q==0 stage node pp, q==1 stage node pp+1
                const int row = pp + q;
                uint_t* dst = &smt[w][row * 36 + r * 4];
#pragma unroll
                for (int j2 = 0; j2 < 4; j2++) {
                    const float lo = q ? tb[2 * j2]     : ta[2 * j2];
                    const float hi = q ? tb[2 * j2 + 1] : ta[2 * j2 + 1];
                    dst[j2] = (uint_t)f2bf(lo) | ((uint_t)f2bf(hi) << 16);
                }
            }
        }
    }
    __syncthreads();

    // MFMA: A = t tile (m=lane&15, k=quad*8+j), two K-halves
    const int m = lane & 15;
    const int quad = lane >> 4;
    const short8 a0 = *(const short8*)&smt[w][m * 36 + quad * 4];
    const short8 a1 = *(const short8*)&smt[w][m * 36 + 16 + quad * 4];

    float lsum[4], lsq[4];
#pragma unroll
    for (int c = 0; c < 4; c++) {
        const short8 b0 = *(const short8*)&wfrag[(size_t)(c * 64 + lane) * 8];
        const short8 b1f = *(const short8*)&wfrag[(size_t)((4 + c) * 64 + lane) * 8];
        f32x4 D = {0.f, 0.f, 0.f, 0.f};
        D = __builtin_amdgcn_mfma_f32_16x16x32_bf16(a0, b0, D, 0, 0, 0);
        D = __builtin_amdgcn_mfma_f32_16x16x32_bf16(a1, b1f, D, 0, 0, 0);
        const float bv = b1[c * 16 + m];
        float s = 0.f, sq = 0.f;
#pragma unroll
        for (int reg = 0; reg < 4; reg++) {
            const float zv = D[reg] + bv;
            if (active) {
                const int node = n0 + quad * 4 + reg;
                __builtin_nontemporal_store(zv, &z[(size_t)node * 64 + c * 16 + m]);
            }
            s += zv;
            sq += zv * zv;
        }
        lsum[c] = s;
        lsq[c] = sq;
    }

    if (active) {
#pragma unroll
        for (int c = 0; c < 4; c++) {
            float s = lsum[c], sq = lsq[c];
            s += __shfl_xor(s, 16, 64);
            s += __shfl_xor(s, 32, 64);
            sq += __shfl_xor(sq, 16, 64);
            sq += __shfl_xor(sq, 32, 64);
            if (quad == 0) {
                atomicAdd(&red[c * 16 + m], s);
                atomicAdd(&red[64 + c * 16 + m], sq);
            }
        }
    }
    __syncthreads();
    if (threadIdx.x < 64) {
        atomicAdd(&colsum[threadIdx.x], red[threadIdx.x]);
        atomicAdd(&colsumsq[threadIdx.x], red[64 + threadIdx.x]);
    }
}

// ---------------- Layer pass B: BN + ReLU + MFMA GEMV(W2) -> h (bf16) -------
// r10: readlane GEMV replaced by the same proven MFMA fragment scheme as
// passA. bnprep fused into the prologue (per-block recompute from per-layer
// colsum slices). Pools removed entirely (deferred to k_pool via linearity).

__global__ __launch_bounds__(256, 4)
void k_passB(const float* __restrict__ z, const float* __restrict__ W2,
             const float* __restrict__ b2, const float* __restrict__ colsum,
             const float* __restrict__ colsumsq, const float* __restrict__ gamma,
             const float* __restrict__ beta, ushort_t* __restrict__ hout) {
    __shared__ ushort_t wfrag[512 * 8];     // W2 B-fragments
    __shared__ float sscale[64], sshift[64];
    __shared__ float ltile[4][16 * 68];     // per-wave [node][col] fp32, pad 68

    const int w = threadIdx.x >> 6;
    const int lane = threadIdx.x & 63;
    const int wid = __builtin_amdgcn_readfirstlane((blockIdx.x << 2) | w);
    const bool active = wid < (N_NODES / 16);
    const int n0 = (active ? wid : 0) * 16;

    for (int s = threadIdx.x; s < 512; s += 256) {
        const int hh = s >> 8, c = (s >> 6) & 3, L = s & 63;
        const int kb = hh * 32 + ((L >> 4) * 8);
        const int out = c * 16 + (L & 15);
        uint_t* dst = (uint_t*)&wfrag[s * 8];
#pragma unroll
        for (int j2 = 0; j2 < 4; j2++) {
            const float lo = W2[(kb + 2 * j2) * 64 + out];
            const float hi = W2[(kb + 2 * j2 + 1) * 64 + out];
            dst[j2] = (uint_t)f2bf(lo) | ((uint_t)f2bf(hi) << 16);
        }
    }
    if (threadIdx.x < 64) {
        const float invn = 1.0f / (float)N_NODES;
        const float mu = colsum[threadIdx.x] * invn;
        const float var = colsumsq[threadIdx.x] * invn - mu * mu;
        const float sc = gamma[threadIdx.x] * rsqrtf(var + BN_EPS);
        sscale[threadIdx.x] = sc;
        sshift[threadIdx.x] = beta[threadIdx.x] - mu * sc;
    }
    __syncthreads();

    const int m = lane & 15;
    const int quad = lane >> 4;

    // A-fragment: row m = node n0+m, k = quad*8+j (two 32-col halves)
    const float* zp = z + (size_t)(n0 + m) * 64;
    const f32x4 za = __builtin_nontemporal_load((const f32x4*)(zp + quad * 8));
    const f32x4 zb = __builtin_nontemporal_load((const f32x4*)(zp + quad * 8 + 4));
    const f32x4 zc = __builtin_nontemporal_load((const f32x4*)(zp + 32 + quad * 8));
    const f32x4 zd = __builtin_nontemporal_load((const f32x4*)(zp + 32 + quad * 8 + 4));
    const f32x4 c0 = *(const f32x4*)&sscale[quad * 8];
    const f32x4 c1 = *(const f32x4*)&sscale[quad * 8 + 4];
    const f32x4 c2 = *(const f32x4*)&sscale[32 + quad * 8];
    const f32x4 c3 = *(const f32x4*)&sscale[32 + quad * 8 + 4];
    const f32x4 h0 = *(const f32x4*)&sshift[quad * 8];
    const f32x4 h1v = *(const f32x4*)&sshift[quad * 8 + 4];
    const f32x4 h2v = *(const f32x4*)&sshift[32 + quad * 8];
    const f32x4 h3v = *(const f32x4*)&sshift[32 + quad * 8 + 4];

    float r0[8], r1[8];
#pragma unroll
    for (int j = 0; j < 4; j++) {
        r0[j]     = fmaxf(fmaf(za[j], c0[j], h0[j]), 0.f);
        r0[4 + j] = fmaxf(fmaf(zb[j], c1[j], h1v[j]), 0.f);
        r1[j]     = fmaxf(fmaf(zc[j], c2[j], h2v[j]), 0.f);
        r1[4 + j] = fmaxf(fmaf(zd[j], c3[j], h3v[j]), 0.f);
    }
    union { uint_t u[4]; short8 v; } pa0, pa1;
#pragma unroll
    for (int j2 = 0; j2 < 4; j2++) {
        pa0.u[j2] = (uint_t)f2bf(r0[2 * j2]) | ((uint_t)f2bf(r0[2 * j2 + 1]) << 16);
        pa1.u[j2] = (uint_t)f2bf(r1[2 * j2]) | ((uint_t)f2bf(r1[2 * j2 + 1]) << 16);
    }
    const short8 a0 = pa0.v;
    const short8 a1 = pa1.v;

#pragma unroll
    for (int c = 0; c < 4; c++) {
        const short8 b0 = *(const short8*)&wfrag[(size_t)(c * 64 + lane) * 8];
        const short8 b1f = *(const short8*)&wfrag[(size_t)((4 + c) * 64 + lane) * 8];
        f32x4 D = {0.f, 0.f, 0.f, 0.f};
        D = __builtin_amdgcn_mfma_f32_16x16x32_bf16(a0, b0, D, 0, 0, 0);
        D = __builtin_amdgcn_mfma_f32_16x16x32_bf16(a1, b1f, D, 0, 0, 0);
        const float bv = b2[c * 16 + m];
#pragma unroll
        for (int reg = 0; reg < 4; reg++)
            ltile[w][(quad * 4 + reg) * 68 + c * 16 + m] = D[reg] + bv;
    }

    // coalesced bf16 writeback (same-wave LDS, compiler inserts lgkmcnt)
    if (active) {
#pragma unroll
        for (int n = 0; n < 16; n++) {
            const float hv = ltile[w][n * 68 + lane];
            hout[(size_t)(n0 + n) * 64 + lane] = f2bf(hv);
        }
    }
}

// ---------------- Pools (deferred; linearity: g_pool = seg_mean(node_pool)) --

#define POOL_CHUNK 64

__global__ void k_pool(const ushort_t* __restrict__ h1, const ushort_t* __restrict__ h2,
                       const ushort_t* __restrict__ h3, const ushort_t* __restrict__ h4,
                       const int* __restrict__ batch, float* __restrict__ node_pool,
                       float* __restrict__ gacc) {
    const int lane = threadIdx.x & 63;
    const int wid = (blockIdx.x << 2) | (threadIdx.x >> 6);
    const int n0 = wid * POOL_CHUNK;
    if (n0 >= N_NODES) return;
    const int n1 = min(N_NODES, n0 + POOL_CHUNK);
    int curg = -1;
    float ga = 0.f;
    for (int n = n0; n < n1; n++) {
        const size_t off = (size_t)n * 64 + lane;
        const float v = bf2f(h1[off]) + bf2f(h2[off]) + bf2f(h3[off]) + bf2f(h4[off]);
        __builtin_nontemporal_store(v, &node_pool[off]);
        const int g = batch[n];
        if (g != curg) {
            if (curg >= 0) atomicAdd(&gacc[curg * 64 + lane], ga);
            ga = 0.f;
            curg = g;
        }
        ga += v;
    }
    if (curg >= 0) atomicAdd(&gacc[curg * 64 + lane], ga);
}

__global__ void k_gfinal(const float* __restrict__ gacc, const float* __restrict__ invg,
                         float* __restrict__ gout) {
    int i = blockIdx.x * blockDim.x + threadIdx.x;
    if (i < NGRAPH * 64) gout[i] = gacc[i] * invg[i >> 6];
}

// ---------------- launch ----------------

extern "C" void kernel_launch(void* const* d_in, const int* in_sizes, int n_in,
                              void* d_out, int out_size, void* d_ws, size_t ws_size,
                              hipStream_t stream) {
    (void)in_sizes; (void)n_in; (void)out_size; (void)ws_size;
    const float* x     = (const float*)d_in[0];
    const int*   ei    = (const int*)d_in[1];
    const int*   batch = (const int*)d_in[2];
    const float* W1    = (const float*)d_in[3];
    const float* b1    = (const float*)d_in[4];
    const float* gamma = (const float*)d_in[5];
    const float* beta  = (const float*)d_in[6];
    const float* W2    = (const float*)d_in[7];
    const float* b2    = (const float*)d_in[8];
    float* out = (float*)d_out;  // [N*64] node_pool, then [G*64] g_pool

    // element offsets (4B units)
    size_t o = 0;
    size_t o_cntS    = o; o += (size_t)NSHARD * N_NODES;
    size_t o_colsum  = o; o += (size_t)NLAYER * 64;
    size_t o_colsq   = o; o += (size_t)NLAYER * 64;
    size_t o_gacc    = o; o += (size_t)NGRAPH * 64;
    size_t zero_elems = o;
    size_t o_cnt     = o; o += N_NODES;
    size_t o_rowptr  = o; o += N_NODES;
    size_t o_bsums   = o; o += 512;
    size_t o_boffs   = o; o += 512;
    size_t o_invdeg  = o; o += N_NODES;
    size_t o_invg    = o; o += NGRAPH;
    size_t o_rank    = o; o += N_EDGES;
    size_t o_csr     = o; o += N_EDGES;
    size_t o_bufA    = o; o += (size_t)N_NODES * 64;   // z, fp32
    size_t o_h1      = o; o += (size_t)N_NODES * 32;   // h1, bf16 (N*64 ushorts)
    size_t o_h2      = o; o += (size_t)N_NODES * 32;
    size_t o_h3      = o; o += (size_t)N_NODES * 32;
    size_t o_xh      = o; o += (size_t)N_NODES * 32;   // x bf16; reused as h4

    int*   wsi = (int*)d_ws;
    float* wsf = (float*)d_ws;
    int*      cntS   = wsi + o_cntS;
    float*    colsum = wsf + o_colsum;
    float*    colsq  = wsf + o_colsq;
    float*    gacc   = wsf + o_gacc;
    int*      cnt    = wsi + o_cnt;
    int*      rowptr = wsi + o_rowptr;
    int*      bsums  = wsi + o_bsums;
    int*      boffs  = wsi + o_boffs;
    float*    invdeg = wsf + o_invdeg;
    float*    invg   = wsf + o_invg;
    int*      rank   = wsi + o_rank;
    int*      csr    = wsi + o_csr;
    float*    bufA   = wsf + o_bufA;
    ushort_t* hb0    = (ushort_t*)(wsi + o_h1);
    ushort_t* hb1    = (ushort_t*)(wsi + o_h2);
    ushort_t* hb2    = (ushort_t*)(wsi + o_h3);
    ushort_t* xh     = (ushort_t*)(wsi + o_xh);   // layer-0 input; layer-3 output

    hipMemsetAsync(d_ws, 0, zero_elems * 4, stream);

    const int eb = (N_EDGES + 255) / 256;
    const int nb = (N_NODES + 255) / 256;  // 391 <= 512

    k_hist<<<eb, 256, 0, stream>>>(ei, cntS, rank);
    k_xcast<<<(N_NODES * 16 + 255) / 256, 256, 0, stream>>>(x, xh);
    k_sumsh<<<nb, 256, 0, stream>>>(cntS, cnt);
    k_scan1<<<nb, 256, 0, stream>>>(cnt, rowptr, bsums);
    k_scan2<<<1, 512, 0, stream>>>(bsums, boffs, nb);
    k_scan3<<<nb, 256, 0, stream>>>(rowptr, boffs);
    k_prep<<<nb, 256, 0, stream>>>(cnt, batch, invdeg, invg);
    k_fill<<<eb, 256, 0, stream>>>(ei, rowptr, cntS, rank, csr);

    const ushort_t* hin[NLAYER]  = {xh,  hb0, hb1, hb2};
    ushort_t*       hoz[NLAYER]  = {hb0, hb1, hb2, xh};   // layer-3 out aliases xh

    const int gridA = (N_NODES / AGG_CHUNK + 3) / 4;  // 1563
    for (int l = 0; l < NLAYER; l++) {
        k_passA<<<gridA, 256, 0, stream>>>(hin[l], W1 + l * 4096, b1 + l * 64,
                                           rowptr, cnt, csr, invdeg,
                                           bufA, colsum + l * 64, colsq + l * 64);
        k_passB<<<gridA, 256, 0, stream>>>(bufA, W2 + l * 4096, b2 + l * 64,
                                           colsum + l * 64, colsq + l * 64,
                                           gamma + l * 64, beta + l * 64, hoz[l]);
    }
    const int gridP = (N_NODES + POOL_CHUNK * 4 - 1) / (POOL_CHUNK * 4);
    k_pool<<<gridP, 256, 0, stream>>>(hb0, hb1, hb2, xh, batch, out, gacc);
    k_gfinal<<<32, 256, 0, stream>>>(gacc, invg, out + (size_t)N_NODES * 64);
}